// Round 17
// baseline (162.221 us; speedup 1.0000x reference)
//
#include <hip/hip_runtime.h>
#include <hip/hip_fp16.h>

#define N_NODES 100000
#define F_IN    128
#define HDIM    64
#define NE      1600000
#define NG      2048
#define NEG_SLOPE 0.2f
#define DCAP    48        // per-dst row capacity (LDS); P(deg>=48) ~ 1e-11/node
#define NB      3125      // buckets of 32 dst nodes
#define BCAP    768       // bucket capacity; Poisson(512)+11sigma < 768
#define NS2     512       // scatter slices
#define SE2     (NE / NS2)   // 3125 edges per slice
#define SCB     64        // scan: buckets per block
#define SCT     128       // scan: slices per LDS tile
#define GEMM_BLKS 1563    // ceil(100000/64)
#define HALF_NB 1563      // scatter bucket-half size (half 1 gets 1562)

typedef unsigned short ushort_t;
typedef short bf16x8 __attribute__((ext_vector_type(8)));
typedef float f32x4 __attribute__((ext_vector_type(4)));

__device__ __forceinline__ ushort_t f2bf(float x) {
    unsigned u = __float_as_uint(x);
    unsigned r = u + 0x7fffu + ((u >> 16) & 1u);   // RNE
    return (ushort_t)(r >> 16);
}
__device__ __forceinline__ float bf2f(ushort_t b) {
    return __uint_as_float(((unsigned)b) << 16);
}
__device__ __forceinline__ float f16lo(unsigned u) {   // f32 from low 16 bits
    __half hh = *(__half*)&u;
    return __half2float(hh);
}

// ws layout (float offsets)
//   xw bf16 : 4096       [6.4M ushort = 3.2M floats]
//   a_src   : 3,204,096  [200,000]
//   a_dst   : 3,404,096  [200,000]
//   p       : 3,604,096  [100,000]
//   base    : 3,704,096  [100,000]
//   evec    : 3,804,096  [100,000]
//   gstart  : 3,904,096  [2,049] int
//   bcnt    : 3,906,148  [3,125] int
//   ebuf    : 3,909,280  [NB*BCAP = 2.4M] int
//   hist    : 6,309,280  [NS2*NB ushort = 0.8M floats]  (slice prefixes, 16-bit)
//   end 7,109,280 floats = 28.4 MB

// ---------- fused front: MFMA GEMM + slice histograms + graph bounds --------
__global__ __launch_bounds__(256) void k_front(const float* __restrict__ node,
        const float* __restrict__ Wg, const float* __restrict__ att_s,
        const float* __restrict__ att_d, ushort_t* __restrict__ xw,
        float* __restrict__ a_src, float* __restrict__ a_dst,
        const int* __restrict__ ei, ushort_t* __restrict__ hist,
        const int* __restrict__ batch, int* __restrict__ gstart) {
    __shared__ __align__(16) char smem[16384];
    int t = threadIdx.x, b = blockIdx.x;
    if (b < GEMM_BLKS) {
        ushort_t* WL = (ushort_t*)smem;      // 8192 bf16 = 16 KB frag table
        for (int i = t; i < 8192; i += 256) {
            int frag = i >> 9, ln = (i >> 3) & 63, j = i & 7;
            int ct = frag >> 2, kt = frag & 3;
            int k = kt * 32 + (ln >> 4) * 8 + j;
            int c = ct * 16 + (ln & 15);
            WL[i] = f2bf(Wg[k * HDIM + c]);
        }
        __syncthreads();

        int lane = t & 63, w = t >> 6;
        int r0 = b * 64 + w * 16;
        int arow = r0 + (lane & 15);
        int arow_c = arow < N_NODES ? arow : N_NODES - 1;
        const float* nr = node + (size_t)arow_c * F_IN + (lane >> 4) * 8;

        bf16x8 a[4];
#pragma unroll
        for (int kt = 0; kt < 4; ++kt) {
            float4 v0 = *(const float4*)(nr + kt * 32);
            float4 v1 = *(const float4*)(nr + kt * 32 + 4);
            bf16x8 av;
            av[0] = (short)f2bf(v0.x); av[1] = (short)f2bf(v0.y);
            av[2] = (short)f2bf(v0.z); av[3] = (short)f2bf(v0.w);
            av[4] = (short)f2bf(v1.x); av[5] = (short)f2bf(v1.y);
            av[6] = (short)f2bf(v1.z); av[7] = (short)f2bf(v1.w);
            a[kt] = av;
        }

        const bf16x8* wp = (const bf16x8*)WL;
        float sv[2][4], dv[2][4];
#pragma unroll
        for (int h = 0; h < 2; ++h)
#pragma unroll
            for (int jj = 0; jj < 4; ++jj) { sv[h][jj] = 0.f; dv[h][jj] = 0.f; }

#pragma unroll
        for (int ct = 0; ct < 4; ++ct) {
            f32x4 acc = {0.f, 0.f, 0.f, 0.f};
#pragma unroll
            for (int kt = 0; kt < 4; ++kt) {
                bf16x8 bfr = wp[(ct * 4 + kt) * 64 + lane];
                acc = __builtin_amdgcn_mfma_f32_16x16x32_bf16(a[kt], bfr, acc, 0, 0, 0);
            }
            int col = ct * 16 + (lane & 15);
            float as_c = att_s[col];
            float ad_c = att_d[col];
            int h = ct >> 1;
#pragma unroll
            for (int jj = 0; jj < 4; ++jj) {
                int r = r0 + (lane >> 4) * 4 + jj;
                if (r < N_NODES) xw[(size_t)r * HDIM + col] = f2bf(acc[jj]);
                sv[h][jj] += acc[jj] * as_c;
                dv[h][jj] += acc[jj] * ad_c;
            }
        }

#pragma unroll
        for (int m = 1; m <= 8; m <<= 1) {
#pragma unroll
            for (int h = 0; h < 2; ++h)
#pragma unroll
                for (int jj = 0; jj < 4; ++jj) {
                    sv[h][jj] += __shfl_xor(sv[h][jj], m, 64);
                    dv[h][jj] += __shfl_xor(dv[h][jj], m, 64);
                }
        }
        if ((lane & 15) == 0) {
            int g = lane >> 4;
#pragma unroll
            for (int jj = 0; jj < 4; ++jj) {
                int r = r0 + g * 4 + jj;
                if (r < N_NODES) {
                    a_src[r * 2 + 0] = sv[0][jj];
                    a_src[r * 2 + 1] = sv[1][jj];
                    a_dst[r * 2 + 0] = dv[0][jj];
                    a_dst[r * 2 + 1] = dv[1][jj];
                }
            }
        }
    } else if (b < GEMM_BLKS + NS2) {
        int* hc = (int*)smem;               // 12.5 KB of the 16 KB
        int bb = b - GEMM_BLKS;
        for (int i = t; i < NB; i += 256) hc[i] = 0;
        __syncthreads();
        int e0 = bb * SE2;
        for (int e = e0 + t; e < e0 + SE2; e += 256)
            atomicAdd(&hc[ei[NE + e] >> 5], 1);
        __syncthreads();
        for (int i = t; i < NB; i += 256)
            hist[(size_t)bb * NB + i] = (ushort_t)hc[i];
    } else {
        int n = (b - GEMM_BLKS - NS2) * 256 + t;
        if (n < N_NODES) {
            int bn = batch[n];
            int bp = (n == 0) ? -1 : batch[n - 1];
            for (int g = bp + 1; g <= bn; ++g) gstart[g] = n;
            if (n == N_NODES - 1)
                for (int g = bn + 1; g <= NG; ++g) gstart[g] = N_NODES;
        }
    }
}

// ---------- scan: tiled, coalesced, 16-bit ------------------------------
// hist holds per-(slice,bucket) counts; after scan it holds the PREFIX over
// slices (<= bucket total <= ~650, fits ushort). The b*BCAP base is added by
// k_scatter at cursor load -> halves scan traffic vs 32-bit offsets.
__global__ __launch_bounds__(256) void k_scan(ushort_t* __restrict__ hist,
        int* __restrict__ bcnt) {
    __shared__ ushort_t tile[SCT][SCB + 2];   // 16.9 KB
    int t = threadIdx.x;
    int b0 = blockIdx.x * SCB;
    int col = t & 63;
    int gb = b0 + col;
    bool own = (t < 64) && (gb < NB);
    int carry = 0;

    for (int tile0 = 0; tile0 < NS2; tile0 += SCT) {
        for (int r = 0; r < SCT; r += 4) {
            int s = r + (t >> 6);
            int bb = b0 + col;
            tile[s][col] = (bb < NB) ? hist[(size_t)(tile0 + s) * NB + bb]
                                     : (ushort_t)0;
        }
        __syncthreads();
        if (t < 64) {
            int c = carry;
#pragma unroll 8
            for (int s = 0; s < SCT; ++s) {
                int v = tile[s][col];
                tile[s][col] = (ushort_t)c;
                c += v;
            }
            carry = c;
        }
        __syncthreads();
        for (int r = 0; r < SCT; r += 4) {
            int s = r + (t >> 6);
            int bb = b0 + col;
            if (bb < NB) hist[(size_t)(tile0 + s) * NB + bb] = tile[s][col];
        }
        __syncthreads();
    }
    if (own) bcnt[gb] = carry;
}

// ---------- scatter: deterministic, LDS cursors, XCD-grouped, 2 halves ------
__global__ __launch_bounds__(256) void k_scatter(const int* __restrict__ ei,
        const ushort_t* __restrict__ pref, int* __restrict__ ebuf) {
    __shared__ int cursor[HALF_NB];     // 6.25 KB
    int t = threadIdx.x;
    int bid = blockIdx.x;
    int x = bid & 7;
    int rest = bid >> 3;                // [0,128)
    int half = rest >> 6;
    int sl = x * 64 + (rest & 63);
    int lo = half * HALF_NB;
    int cnt_h = half ? (NB - HALF_NB) : HALF_NB;   // 1562 : 1563
    for (int i = t; i < cnt_h; i += 256)
        cursor[i] = (lo + i) * BCAP + (int)pref[(size_t)sl * NB + lo + i];
    __syncthreads();
    int e0 = sl * SE2;
    for (int e = e0 + t; e < e0 + SE2; e += 256) {
        int d = ei[NE + e];
        int bb = d >> 5;
        unsigned idx = (unsigned)(bb - lo);
        if (idx < (unsigned)cnt_h) {
            int s = ei[e];
            int pos = atomicAdd(&cursor[idx], 1);
            if (pos < (bb + 1) * BCAP) ebuf[pos] = s | ((d & 31) << 17);
        }
    }
}

// ---------- K2: GAT aggregation, block per bucket, 2 cols/lane (r15 best) ---
__global__ __launch_bounds__(256) void k_gat(const int* __restrict__ bcnt,
        const int* __restrict__ ebuf, const ushort_t* __restrict__ xw,
        const float* __restrict__ a_src, const float* __restrict__ a_dst,
        const float* __restrict__ bias, const float* __restrict__ wrel,
        const float* __restrict__ wroot, const float* __restrict__ brel,
        float* __restrict__ x_out, float* __restrict__ p,
        float* __restrict__ base) {
    __shared__ int2 rows[32][DCAP];    // 12,288 B: (sByteOff = s<<7, half2 e)
    __shared__ int rowcnt[32];
    __shared__ float adld[64];
    int t = threadIdx.x, b = blockIdx.x;
    if (t < 32) rowcnt[t] = 0;
    if (t < 64) adld[t] = a_dst[b * 64 + t];
    __syncthreads();

    int cnt = bcnt[b]; if (cnt > BCAP) cnt = BCAP;
    const int* eb = ebuf + b * BCAP;
    for (int i = t; i < cnt; i += 256) {
        int v = eb[i];
        int s = v & 0x1FFFF;
        int dl = v >> 17;
        float2 asp = *(const float2*)(a_src + 2 * s);
        float l0 = asp.x + adld[2 * dl];     l0 = l0 > 0.f ? l0 : NEG_SLOPE * l0;
        float l1 = asp.y + adld[2 * dl + 1]; l1 = l1 > 0.f ? l1 : NEG_SLOPE * l1;
        __half2 hp = __floats2half2_rn(__expf(l0), __expf(l1));
        int pos = atomicAdd(&rowcnt[dl], 1);
        if (pos < DCAP) rows[dl][pos] = make_int2(s << 7, *(int*)&hp);
    }
    __syncthreads();

    int lane = t & 63, wv = t >> 6;
    int half = lane >> 5;
    int li = lane & 31;
    int h2 = li >> 4;                        // head of this lane's col pair
    unsigned shift = (unsigned)(li & 16);    // w extract shift = h2*16
    unsigned colOff = (unsigned)(li << 2);   // dword offset within 128B row
    const char* xwB = (const char*)xw;
    float2 bias2  = *(const float2*)(bias + 2 * li);
    float2 wrel2  = *(const float2*)(wrel + 2 * li);
    float2 wroot2 = *(const float2*)(wroot + 2 * li);
    float br = brel[0];

#pragma unroll
    for (int q8 = 0; q8 < 8; ++q8) {
        int dl = wv * 8 + q8;
        int d = b * 32 + dl;
        int nv = rowcnt[dl]; if (nv > DCAP) nv = DCAP;
        const int2* rw = rows[dl];
        float aL0 = 0.f, aH0 = 0.f, aL1 = 0.f, aH1 = 0.f, den = 0.f;
        int j = 0;
        for (; j + 4 <= nv; j += 4) {        // 4 edges = 2 per half
            int2 qa = rw[j + half];
            int2 qb = rw[j + 2 + half];
            unsigned ua = *(const unsigned*)(xwB + ((unsigned)qa.x + colOff));
            unsigned ub = *(const unsigned*)(xwB + ((unsigned)qb.x + colOff));
            float wa = f16lo(((unsigned)qa.y) >> shift);
            float wb = f16lo(((unsigned)qb.y) >> shift);
            aL0 += wa * __uint_as_float(ua << 16);
            aH0 += wa * __uint_as_float(ua & 0xFFFF0000u);
            den += wa;
            aL1 += wb * __uint_as_float(ub << 16);
            aH1 += wb * __uint_as_float(ub & 0xFFFF0000u);
            den += wb;
        }
        for (; j < nv; j += 2) {             // tail: 0..3 edges
            int jj = j + half;
            if (jj < nv) {
                int2 qa = rw[jj];
                unsigned ua = *(const unsigned*)(xwB + ((unsigned)qa.x + colOff));
                float wa = f16lo(((unsigned)qa.y) >> shift);
                aL0 += wa * __uint_as_float(ua << 16);
                aH0 += wa * __uint_as_float(ua & 0xFFFF0000u);
                den += wa;
            }
        }
        float accL = aL0 + aL1, accH = aH0 + aH1;
        accL += __shfl_xor(accL, 32, 64);
        accH += __shfl_xor(accH, 32, 64);
        den  += __shfl_xor(den, 32, 64);

        // self loop (fp32 exp for own head)
        float2 asd = *(const float2*)(a_src + 2 * d);
        float lgs = (h2 ? asd.y : asd.x) + adld[2 * dl + h2];
        lgs = lgs > 0.f ? lgs : NEG_SLOPE * lgs;
        float es = __expf(lgs);
        unsigned us = *(const unsigned*)(xwB + (((unsigned)d << 7) + colOff));
        float denT = den + es;
        float vL = (accL + es * __uint_as_float(us << 16)) / denT + bias2.x;
        float vH = (accH + es * __uint_as_float(us & 0xFFFF0000u)) / denT + bias2.y;
        if (half == 0)
            *(float2*)(x_out + (size_t)d * HDIM + 2 * li) = make_float2(vL, vH);

        float pv = vL * wrel2.x + vH * wrel2.y;
        float rv = vL * wroot2.x + vH * wroot2.y;
        if (half) { pv = 0.f; rv = 0.f; }
#pragma unroll
        for (int m = 32; m >= 1; m >>= 1) {
            pv += __shfl_xor(pv, m, 64);
            rv += __shfl_xor(rv, m, 64);
        }
        if (lane == 0) { p[d] = pv; base[d] = rv + br; }
    }
}

// ---------- K3: score aggregation per bucket -> evec (per-wave acc) ---------
__global__ __launch_bounds__(256) void k_score(const int* __restrict__ bcnt,
        const int* __restrict__ ebuf, const float* __restrict__ pp,
        const float* __restrict__ base, float* __restrict__ evec) {
    __shared__ float sa[4][32];
    int t = threadIdx.x, b = blockIdx.x;
    if (t < 128) (&sa[0][0])[t] = 0.f;
    __syncthreads();
    int cnt = bcnt[b]; if (cnt > BCAP) cnt = BCAP;
    const int* eb = ebuf + b * BCAP;
    int wv = t >> 6;
    for (int i = t; i < cnt; i += 256) {
        int v = eb[i];
        atomicAdd(&sa[wv][v >> 17], pp[v & 0x1FFFF]);
    }
    __syncthreads();
    if (t < 32) {
        int n = b * 32 + t;
        evec[n] = __expf(sa[0][t] + sa[1][t] + sa[2][t] + sa[3][t] + base[n]);
    }
}

// ---------- K4: per-graph pooled embedding ----------
__global__ __launch_bounds__(256) void k_pool(const float* __restrict__ x,
        const float* __restrict__ evec, const int* __restrict__ gstart,
        float* __restrict__ emb) {
    int g = blockIdx.x;
    int lane = threadIdx.x & 63;
    int wave = threadIdx.x >> 6;
    int beg = gstart[g], end = gstart[g + 1];
    float acc = 0.f, esum = 0.f;
    for (int n = beg + wave; n < end; n += 4) {
        float ev = evec[n];
        acc += ev * x[(size_t)n * HDIM + lane];
        esum += ev;
    }
    __shared__ float sacc[4][HDIM];
    __shared__ float ses[4];
    sacc[wave][lane] = acc;
    if (lane == 0) ses[wave] = esum;
    __syncthreads();
    if (wave == 0) {
        float a = sacc[0][lane] + sacc[1][lane] + sacc[2][lane] + sacc[3][lane];
        float es = ses[0] + ses[1] + ses[2] + ses[3];
        emb[(size_t)g * HDIM + lane] = (es > 0.f) ? (a / es) : 0.f;
    }
}

extern "C" void kernel_launch(void* const* d_in, const int* in_sizes, int n_in,
                              void* d_out, int out_size, void* d_ws, size_t ws_size,
                              hipStream_t stream) {
    const float* node  = (const float*)d_in[0];
    const int*   ei    = (const int*)d_in[1];
    const int*   batch = (const int*)d_in[2];
    const float* Wg    = (const float*)d_in[3];
    const float* att_s = (const float*)d_in[4];
    const float* att_d = (const float*)d_in[5];
    const float* bias  = (const float*)d_in[6];
    const float* wrel  = (const float*)d_in[7];
    const float* brel  = (const float*)d_in[8];
    const float* wroot = (const float*)d_in[9];

    float* out = (float*)d_out;
    float* emb = out + (size_t)N_NODES * HDIM;

    float*    ws     = (float*)d_ws;
    ushort_t* xw     = (ushort_t*)(ws + 4096);
    float*    a_src  = ws + 3204096;
    float*    a_dst  = ws + 3404096;
    float*    p      = ws + 3604096;
    float*    base   = ws + 3704096;
    float*    evec   = ws + 3804096;
    int*      gstart = (int*)(ws + 3904096);
    int*      bcnt   = (int*)(ws + 3906148);
    int*      ebuf   = (int*)(ws + 3909280);
    ushort_t* hist   = (ushort_t*)(ws + 6309280);

    k_front<<<GEMM_BLKS + NS2 + 391, 256, 0, stream>>>(node, Wg, att_s, att_d,
                                                       xw, a_src, a_dst,
                                                       ei, hist, batch, gstart);
    k_scan<<<(NB + SCB - 1) / SCB, 256, 0, stream>>>(hist, bcnt);
    k_scatter<<<2 * NS2, 256, 0, stream>>>(ei, hist, ebuf);
    k_gat<<<NB, 256, 0, stream>>>(bcnt, ebuf, xw, a_src, a_dst,
                                  bias, wrel, wroot, brel, out, p, base);
    k_score<<<NB, 256, 0, stream>>>(bcnt, ebuf, p, base, evec);
    k_pool<<<NG, 256, 0, stream>>>(out, evec, gstart, emb);
}

// Round 18
// 153.592 us; speedup vs baseline: 1.0562x; 1.0562x over previous
//
#include <hip/hip_runtime.h>
#include <hip/hip_fp16.h>

#define N_NODES 100000
#define F_IN    128
#define HDIM    64
#define NE      1600000
#define NG      2048
#define NEG_SLOPE 0.2f
#define DCAP    48        // per-dst row capacity (LDS); P(deg>=48) ~ 1e-11/node
#define NB      3125      // buckets of 32 dst nodes
#define BCAP    768       // bucket capacity; Poisson(512)+11sigma < 768
#define NS2     512       // scatter slices
#define SE2     (NE / NS2)   // 3125 edges per slice
#define SCB     64        // scan: buckets per block
#define SCT     128       // scan: slices per LDS tile
#define GEMM_BLKS 1563    // ceil(100000/64)
#define HALF_NB 1563      // scatter bucket-half size (half 1 gets 1562)

typedef unsigned short ushort_t;
typedef short bf16x8 __attribute__((ext_vector_type(8)));
typedef float f32x4 __attribute__((ext_vector_type(4)));

__device__ __forceinline__ ushort_t f2bf(float x) {
    unsigned u = __float_as_uint(x);
    unsigned r = u + 0x7fffu + ((u >> 16) & 1u);   // RNE
    return (ushort_t)(r >> 16);
}
__device__ __forceinline__ float bf2f(ushort_t b) {
    return __uint_as_float(((unsigned)b) << 16);
}
__device__ __forceinline__ float f16lo(unsigned u) {   // f32 from low 16 bits
    __half hh = *(__half*)&u;
    return __half2float(hh);
}

// ws layout (float offsets)
//   xw bf16 : 4096       [6.4M ushort = 3.2M floats]
//   a_src   : 3,204,096  [200,000]
//   a_dst   : 3,404,096  [200,000]
//   p       : 3,604,096  [100,000]
//   base    : 3,704,096  [100,000]
//   evec    : 3,804,096  [100,000]
//   gstart  : 3,904,096  [2,049] int
//   bcnt    : 3,906,148  [3,125] int
//   ebuf    : 3,909,280  [NB*BCAP = 2.4M] int
//   hist    : 6,309,280  [NS2*NB = 1.6M] int
//   end 7,909,280 floats = 31.6 MB

// ---------- fused front: MFMA GEMM + slice histograms + graph bounds --------
__global__ __launch_bounds__(256) void k_front(const float* __restrict__ node,
        const float* __restrict__ Wg, const float* __restrict__ att_s,
        const float* __restrict__ att_d, ushort_t* __restrict__ xw,
        float* __restrict__ a_src, float* __restrict__ a_dst,
        const int* __restrict__ ei, int* __restrict__ hist,
        const int* __restrict__ batch, int* __restrict__ gstart) {
    __shared__ __align__(16) char smem[16384];
    int t = threadIdx.x, b = blockIdx.x;
    if (b < GEMM_BLKS) {
        ushort_t* WL = (ushort_t*)smem;      // 8192 bf16 = 16 KB frag table
        for (int i = t; i < 8192; i += 256) {
            int frag = i >> 9, ln = (i >> 3) & 63, j = i & 7;
            int ct = frag >> 2, kt = frag & 3;
            int k = kt * 32 + (ln >> 4) * 8 + j;
            int c = ct * 16 + (ln & 15);
            WL[i] = f2bf(Wg[k * HDIM + c]);
        }
        __syncthreads();

        int lane = t & 63, w = t >> 6;
        int r0 = b * 64 + w * 16;
        int arow = r0 + (lane & 15);
        int arow_c = arow < N_NODES ? arow : N_NODES - 1;
        const float* nr = node + (size_t)arow_c * F_IN + (lane >> 4) * 8;

        bf16x8 a[4];
#pragma unroll
        for (int kt = 0; kt < 4; ++kt) {
            float4 v0 = *(const float4*)(nr + kt * 32);
            float4 v1 = *(const float4*)(nr + kt * 32 + 4);
            bf16x8 av;
            av[0] = (short)f2bf(v0.x); av[1] = (short)f2bf(v0.y);
            av[2] = (short)f2bf(v0.z); av[3] = (short)f2bf(v0.w);
            av[4] = (short)f2bf(v1.x); av[5] = (short)f2bf(v1.y);
            av[6] = (short)f2bf(v1.z); av[7] = (short)f2bf(v1.w);
            a[kt] = av;
        }

        const bf16x8* wp = (const bf16x8*)WL;
        float sv[2][4], dv[2][4];
#pragma unroll
        for (int h = 0; h < 2; ++h)
#pragma unroll
            for (int jj = 0; jj < 4; ++jj) { sv[h][jj] = 0.f; dv[h][jj] = 0.f; }

#pragma unroll
        for (int ct = 0; ct < 4; ++ct) {
            f32x4 acc = {0.f, 0.f, 0.f, 0.f};
#pragma unroll
            for (int kt = 0; kt < 4; ++kt) {
                bf16x8 bfr = wp[(ct * 4 + kt) * 64 + lane];
                acc = __builtin_amdgcn_mfma_f32_16x16x32_bf16(a[kt], bfr, acc, 0, 0, 0);
            }
            int col = ct * 16 + (lane & 15);
            float as_c = att_s[col];
            float ad_c = att_d[col];
            int h = ct >> 1;
#pragma unroll
            for (int jj = 0; jj < 4; ++jj) {
                int r = r0 + (lane >> 4) * 4 + jj;
                if (r < N_NODES) xw[(size_t)r * HDIM + col] = f2bf(acc[jj]);
                sv[h][jj] += acc[jj] * as_c;
                dv[h][jj] += acc[jj] * ad_c;
            }
        }

#pragma unroll
        for (int m = 1; m <= 8; m <<= 1) {
#pragma unroll
            for (int h = 0; h < 2; ++h)
#pragma unroll
                for (int jj = 0; jj < 4; ++jj) {
                    sv[h][jj] += __shfl_xor(sv[h][jj], m, 64);
                    dv[h][jj] += __shfl_xor(dv[h][jj], m, 64);
                }
        }
        if ((lane & 15) == 0) {
            int g = lane >> 4;
#pragma unroll
            for (int jj = 0; jj < 4; ++jj) {
                int r = r0 + g * 4 + jj;
                if (r < N_NODES) {
                    a_src[r * 2 + 0] = sv[0][jj];
                    a_src[r * 2 + 1] = sv[1][jj];
                    a_dst[r * 2 + 0] = dv[0][jj];
                    a_dst[r * 2 + 1] = dv[1][jj];
                }
            }
        }
    } else if (b < GEMM_BLKS + NS2) {
        int* hc = (int*)smem;               // 12.5 KB of the 16 KB
        int bb = b - GEMM_BLKS;
        for (int i = t; i < NB; i += 256) hc[i] = 0;
        __syncthreads();
        int e0 = bb * SE2;
        for (int e = e0 + t; e < e0 + SE2; e += 256)
            atomicAdd(&hc[ei[NE + e] >> 5], 1);
        __syncthreads();
        for (int i = t; i < NB; i += 256) hist[bb * NB + i] = hc[i];
    } else {
        int n = (b - GEMM_BLKS - NS2) * 256 + t;
        if (n < N_NODES) {
            int bn = batch[n];
            int bp = (n == 0) ? -1 : batch[n - 1];
            for (int g = bp + 1; g <= bn; ++g) gstart[g] = n;
            if (n == N_NODES - 1)
                for (int g = bn + 1; g <= NG; ++g) gstart[g] = N_NODES;
        }
    }
}

// ---------- scan: tiled, coalesced; 49 blocks x 64 buckets ----------
__global__ __launch_bounds__(256) void k_scan(int* __restrict__ hist,
        int* __restrict__ bcnt) {
    __shared__ int tile[SCT][SCB + 1];   // 33.3 KB, padded
    int t = threadIdx.x;
    int b0 = blockIdx.x * SCB;
    int col = t & 63;
    int gb = b0 + col;
    bool own = (t < 64) && (gb < NB);
    int carry = own ? gb * BCAP : 0;

    for (int tile0 = 0; tile0 < NS2; tile0 += SCT) {
        for (int r = 0; r < SCT; r += 4) {
            int s = r + (t >> 6);
            int bb = b0 + col;
            tile[s][col] = (bb < NB) ? hist[(tile0 + s) * NB + bb] : 0;
        }
        __syncthreads();
        if (t < 64) {
            int c = carry;
#pragma unroll 8
            for (int s = 0; s < SCT; ++s) {
                int v = tile[s][col];
                tile[s][col] = c;
                c += v;
            }
            carry = c;
        }
        __syncthreads();
        for (int r = 0; r < SCT; r += 4) {
            int s = r + (t >> 6);
            int bb = b0 + col;
            if (bb < NB) hist[(tile0 + s) * NB + bb] = tile[s][col];
        }
        __syncthreads();
    }
    if (own) bcnt[gb] = carry - gb * BCAP;
}

// ---------- scatter: deterministic, LDS cursors, XCD-grouped, 2 halves ------
__global__ __launch_bounds__(256) void k_scatter(const int* __restrict__ ei,
        const int* __restrict__ off, int* __restrict__ ebuf) {
    __shared__ int cursor[HALF_NB];     // 6.25 KB
    int t = threadIdx.x;
    int bid = blockIdx.x;
    int x = bid & 7;
    int rest = bid >> 3;                // [0,128)
    int half = rest >> 6;
    int sl = x * 64 + (rest & 63);
    int lo = half * HALF_NB;
    int cnt_h = half ? (NB - HALF_NB) : HALF_NB;   // 1562 : 1563
    for (int i = t; i < cnt_h; i += 256) cursor[i] = off[sl * NB + lo + i];
    __syncthreads();
    int e0 = sl * SE2;
    for (int e = e0 + t; e < e0 + SE2; e += 256) {
        int d = ei[NE + e];
        int bb = d >> 5;
        unsigned idx = (unsigned)(bb - lo);
        if (idx < (unsigned)cnt_h) {
            int s = ei[e];
            int pos = atomicAdd(&cursor[idx], 1);
            if (pos < (bb + 1) * BCAP) ebuf[pos] = s | ((d & 31) << 17);
        }
    }
}

// ---------- K2: GAT aggregation, block per bucket, 2 cols/lane gather -------
__global__ __launch_bounds__(256) void k_gat(const int* __restrict__ bcnt,
        const int* __restrict__ ebuf, const ushort_t* __restrict__ xw,
        const float* __restrict__ a_src, const float* __restrict__ a_dst,
        const float* __restrict__ bias, const float* __restrict__ wrel,
        const float* __restrict__ wroot, const float* __restrict__ brel,
        float* __restrict__ x_out, float* __restrict__ p,
        float* __restrict__ base) {
    __shared__ int2 rows[32][DCAP];    // 12,288 B: (sByteOff = s<<7, half2 e)
    __shared__ int rowcnt[32];
    __shared__ float adld[64];
    int t = threadIdx.x, b = blockIdx.x;
    if (t < 32) rowcnt[t] = 0;
    if (t < 64) adld[t] = a_dst[b * 64 + t];
    __syncthreads();

    int cnt = bcnt[b]; if (cnt > BCAP) cnt = BCAP;
    const int* eb = ebuf + b * BCAP;
    for (int i = t; i < cnt; i += 256) {
        int v = eb[i];
        int s = v & 0x1FFFF;
        int dl = v >> 17;
        float2 asp = *(const float2*)(a_src + 2 * s);
        float l0 = asp.x + adld[2 * dl];     l0 = l0 > 0.f ? l0 : NEG_SLOPE * l0;
        float l1 = asp.y + adld[2 * dl + 1]; l1 = l1 > 0.f ? l1 : NEG_SLOPE * l1;
        __half2 hp = __floats2half2_rn(__expf(l0), __expf(l1));
        int pos = atomicAdd(&rowcnt[dl], 1);
        if (pos < DCAP) rows[dl][pos] = make_int2(s << 7, *(int*)&hp);
    }
    __syncthreads();

    int lane = t & 63, wv = t >> 6;
    int half = lane >> 5;
    int li = lane & 31;
    int h2 = li >> 4;                        // head of this lane's col pair
    unsigned shift = (unsigned)(li & 16);    // w extract shift = h2*16
    unsigned colOff = (unsigned)(li << 2);   // dword offset within 128B row
    const char* xwB = (const char*)xw;
    float2 bias2  = *(const float2*)(bias + 2 * li);
    float2 wrel2  = *(const float2*)(wrel + 2 * li);
    float2 wroot2 = *(const float2*)(wroot + 2 * li);
    float br = brel[0];

#pragma unroll
    for (int q8 = 0; q8 < 8; ++q8) {
        int dl = wv * 8 + q8;
        int d = b * 32 + dl;
        int nv = rowcnt[dl]; if (nv > DCAP) nv = DCAP;
        const int2* rw = rows[dl];
        float aL0 = 0.f, aH0 = 0.f, aL1 = 0.f, aH1 = 0.f, den = 0.f;
        int j = 0;
        for (; j + 4 <= nv; j += 4) {        // 4 edges = 2 per half
            int2 qa = rw[j + half];
            int2 qb = rw[j + 2 + half];
            unsigned ua = *(const unsigned*)(xwB + ((unsigned)qa.x + colOff));
            unsigned ub = *(const unsigned*)(xwB + ((unsigned)qb.x + colOff));
            float wa = f16lo(((unsigned)qa.y) >> shift);
            float wb = f16lo(((unsigned)qb.y) >> shift);
            aL0 += wa * __uint_as_float(ua << 16);
            aH0 += wa * __uint_as_float(ua & 0xFFFF0000u);
            den += wa;
            aL1 += wb * __uint_as_float(ub << 16);
            aH1 += wb * __uint_as_float(ub & 0xFFFF0000u);
            den += wb;
        }
        for (; j < nv; j += 2) {             // tail: 0..3 edges
            int jj = j + half;
            if (jj < nv) {
                int2 qa = rw[jj];
                unsigned ua = *(const unsigned*)(xwB + ((unsigned)qa.x + colOff));
                float wa = f16lo(((unsigned)qa.y) >> shift);
                aL0 += wa * __uint_as_float(ua << 16);
                aH0 += wa * __uint_as_float(ua & 0xFFFF0000u);
                den += wa;
            }
        }
        float accL = aL0 + aL1, accH = aH0 + aH1;
        accL += __shfl_xor(accL, 32, 64);
        accH += __shfl_xor(accH, 32, 64);
        den  += __shfl_xor(den, 32, 64);

        // self loop (fp32 exp for own head)
        float2 asd = *(const float2*)(a_src + 2 * d);
        float lgs = (h2 ? asd.y : asd.x) + adld[2 * dl + h2];
        lgs = lgs > 0.f ? lgs : NEG_SLOPE * lgs;
        float es = __expf(lgs);
        unsigned us = *(const unsigned*)(xwB + (((unsigned)d << 7) + colOff));
        float denT = den + es;
        float vL = (accL + es * __uint_as_float(us << 16)) / denT + bias2.x;
        float vH = (accH + es * __uint_as_float(us & 0xFFFF0000u)) / denT + bias2.y;
        if (half == 0)
            *(float2*)(x_out + (size_t)d * HDIM + 2 * li) = make_float2(vL, vH);

        float pv = vL * wrel2.x + vH * wrel2.y;
        float rv = vL * wroot2.x + vH * wroot2.y;
        if (half) { pv = 0.f; rv = 0.f; }
#pragma unroll
        for (int m = 32; m >= 1; m >>= 1) {
            pv += __shfl_xor(pv, m, 64);
            rv += __shfl_xor(rv, m, 64);
        }
        if (lane == 0) { p[d] = pv; base[d] = rv + br; }
    }
}

// ---------- K3: score aggregation per bucket -> evec (per-wave acc) ---------
__global__ __launch_bounds__(256) void k_score(const int* __restrict__ bcnt,
        const int* __restrict__ ebuf, const float* __restrict__ pp,
        const float* __restrict__ base, float* __restrict__ evec) {
    __shared__ float sa[4][32];
    int t = threadIdx.x, b = blockIdx.x;
    if (t < 128) (&sa[0][0])[t] = 0.f;
    __syncthreads();
    int cnt = bcnt[b]; if (cnt > BCAP) cnt = BCAP;
    const int* eb = ebuf + b * BCAP;
    int wv = t >> 6;
    for (int i = t; i < cnt; i += 256) {
        int v = eb[i];
        atomicAdd(&sa[wv][v >> 17], pp[v & 0x1FFFF]);
    }
    __syncthreads();
    if (t < 32) {
        int n = b * 32 + t;
        evec[n] = __expf(sa[0][t] + sa[1][t] + sa[2][t] + sa[3][t] + base[n]);
    }
}

// ---------- K4: per-graph pooled embedding ----------
__global__ __launch_bounds__(256) void k_pool(const float* __restrict__ x,
        const float* __restrict__ evec, const int* __restrict__ gstart,
        float* __restrict__ emb) {
    int g = blockIdx.x;
    int lane = threadIdx.x & 63;
    int wave = threadIdx.x >> 6;
    int beg = gstart[g], end = gstart[g + 1];
    float acc = 0.f, esum = 0.f;
    for (int n = beg + wave; n < end; n += 4) {
        float ev = evec[n];
        acc += ev * x[(size_t)n * HDIM + lane];
        esum += ev;
    }
    __shared__ float sacc[4][HDIM];
    __shared__ float ses[4];
    sacc[wave][lane] = acc;
    if (lane == 0) ses[wave] = esum;
    __syncthreads();
    if (wave == 0) {
        float a = sacc[0][lane] + sacc[1][lane] + sacc[2][lane] + sacc[3][lane];
        float es = ses[0] + ses[1] + ses[2] + ses[3];
        emb[(size_t)g * HDIM + lane] = (es > 0.f) ? (a / es) : 0.f;
    }
}

extern "C" void kernel_launch(void* const* d_in, const int* in_sizes, int n_in,
                              void* d_out, int out_size, void* d_ws, size_t ws_size,
                              hipStream_t stream) {
    const float* node  = (const float*)d_in[0];
    const int*   ei    = (const int*)d_in[1];
    const int*   batch = (const int*)d_in[2];
    const float* Wg    = (const float*)d_in[3];
    const float* att_s = (const float*)d_in[4];
    const float* att_d = (const float*)d_in[5];
    const float* bias  = (const float*)d_in[6];
    const float* wrel  = (const float*)d_in[7];
    const float* brel  = (const float*)d_in[8];
    const float* wroot = (const float*)d_in[9];

    float* out = (float*)d_out;
    float* emb = out + (size_t)N_NODES * HDIM;

    float*    ws     = (float*)d_ws;
    ushort_t* xw     = (ushort_t*)(ws + 4096);
    float*    a_src  = ws + 3204096;
    float*    a_dst  = ws + 3404096;
    float*    p      = ws + 3604096;
    float*    base   = ws + 3704096;
    float*    evec   = ws + 3804096;
    int*      gstart = (int*)(ws + 3904096);
    int*      bcnt   = (int*)(ws + 3906148);
    int*      ebuf   = (int*)(ws + 3909280);
    int*      hist   = (int*)(ws + 6309280);

    k_front<<<GEMM_BLKS + NS2 + 391, 256, 0, stream>>>(node, Wg, att_s, att_d,
                                                       xw, a_src, a_dst,
                                                       ei, hist, batch, gstart);
    k_scan<<<(NB + SCB - 1) / SCB, 256, 0, stream>>>(hist, bcnt);
    k_scatter<<<2 * NS2, 256, 0, stream>>>(ei, hist, ebuf);
    k_gat<<<NB, 256, 0, stream>>>(bcnt, ebuf, xw, a_src, a_dst,
                                  bias, wrel, wroot, brel, out, p, base);
    k_score<<<NB, 256, 0, stream>>>(bcnt, ebuf, p, base, evec);
    k_pool<<<NG, 256, 0, stream>>>(out, evec, gstart, emb);
}